// Round 4
// baseline (664.291 us; speedup 1.0000x reference)
//
#include <hip/hip_runtime.h>
#include <hip/hip_bf16.h>

#define B_ 4
#define N_ 1024
#define NB_ 32
#define C_ 384
#define CZ_ 128
#define NSITES (B_ * N_)   // 4096
#define EPSV 1e-6f
#define THREADS 512
#define NSTRIP 4           // N split: 4 strips x 96 cols
#define SCOLS 96
#define NKZ 4              // z k-chunks (128/32)
#define NKS 12             // s k-chunks (384/32)
#define NCH 16             // unified chunks (0..3 = z@Wz, 4..15 = s@Ws)
#define SITES_PER_BLK 32
#define NBLK (NSITES / SITES_PER_BLK)   // 128
#define SITES_PER_WAVE 4                // 8 waves/block
#define WCHUNK_U16 3072                 // 4 q * 96 d * 8 e
#define WSTRIP_U16 (NCH * WCHUNK_U16)   // 49152 u16 = 98304 B

typedef unsigned short u16;
typedef unsigned int u32;
typedef __bf16 bf16x8 __attribute__((ext_vector_type(8)));
typedef float f32x4 __attribute__((ext_vector_type(4)));

__device__ __forceinline__ u16 f2bf(float f) {
    return __builtin_bit_cast(u16, __float2bfloat16(f));
}
__device__ __forceinline__ u32 pk2(float lo, float hi) {
    return ((u32)f2bf(hi) << 16) | f2bf(lo);
}
__device__ __forceinline__ float bfbits2f(u16 u) {
    union { float f; u32 i; } x;
    x.i = ((u32)u) << 16;
    return x.f;
}
__device__ __forceinline__ bf16x8 mk8(float4 lo, float4 hi) {
    union { u32 u[4]; bf16x8 v; } x;
    x.u[0] = pk2(lo.x, lo.y); x.u[1] = pk2(lo.z, lo.w);
    x.u[2] = pk2(hi.x, hi.y); x.u[3] = pk2(hi.z, hi.w);
    return x.v;
}

// Strip-major, chunk-major workspace matching the LINEAR global_load_lds
// write order:  ws[(((st*16 + c)*4 + q)*96 + d)*8 + e] = bf16(W[k][st*96+d]),
// k = (c<4 ? c : c-4)*32 + q*8 + e  (W = Wz for c<4, Ws for c>=4).
// A straight 98304-B DMA of strip st gives LDS [c][q][d][8]: the b-frag
// ds_read_b128 hits 16 consecutive 16-B slots (conflict-free, ==R1 layout,
// SQ_LDS_BANK_CONFLICT measured 0).
__global__ void prep_weights(const float* __restrict__ Ws, const float* __restrict__ Wz,
                             u16* __restrict__ wsAll) {
    int idx = blockIdx.x * 256 + threadIdx.x;
    if (idx >= NSTRIP * WSTRIP_U16) return;
    int e = idx & 7;
    int t = idx >> 3;
    int d = t % SCOLS;
    int u = t / SCOLS;
    int q = u & 3;
    int v = u >> 2;
    int c = v & 15;
    int st = v >> 4;
    int col = st * SCOLS + d;
    float val;
    if (c < NKZ) {
        int k = c * 32 + q * 8 + e;
        val = Wz[k * C_ + col];
    } else {
        int k = (c - NKZ) * 32 + q * 8 + e;
        val = Ws[k * C_ + col];
    }
    wsAll[idx] = f2bf(val);
}

// Weight-stationary kernel. Block = 512 thr (8 waves), one 96-col strip,
// 32 sites. Weights (96 KB) DMA'd to LDS ONCE; one __syncthreads; after
// that ZERO barriers — each wave independently processes 4 sites
// (32 rows x 96 cols each, acc[2][6]), with a 4-chunk register A-prefetch
// ring that pipelines across site boundaries. Pre-LN result written
// straight to `out`; ln_kernel normalizes in-place.
__global__ __launch_bounds__(THREADS, 2)
void fused_msg_kernel(const float* __restrict__ s_i,
                      const float* __restrict__ s_ij,
                      const float* __restrict__ m_ij,
                      const float* __restrict__ z_ij,
                      const u16* __restrict__ wsAll,
                      float* __restrict__ out) {
    __shared__ u16 ldsW[WSTRIP_U16];   // 98304 B -> 1 block/CU

    const int tid = threadIdx.x;
    const int wave = tid >> 6;
    const int lane = tid & 63;
    const int q = lane >> 4;
    const int ln = lane & 15;

    // blockIdx decode: strip-siblings (same blk, strips 0..3) share
    // g mod 8 -> same XCD -> A rows L2-shared 4x.
    const int g = blockIdx.x;                 // 0..511
    const int xcd = g & 7;
    const int strip = (g >> 3) & 3;
    const int blk = xcd * (NBLK / 8) + (g >> 5);   // 0..127, bijective

    // ---- stage this strip's weights: 12 x 16B per thread, linear DMA ----
    {
        const char* src = (const char*)(wsAll + (long)strip * WSTRIP_U16);
        char* dst = (char*)&ldsW[0];
        #pragma unroll
        for (int i = 0; i < 12; ++i) {
            int o = i * 8192 + tid * 16;
            __builtin_amdgcn_global_load_lds(
                (const __attribute__((address_space(1))) void*)(src + o),
                (__attribute__((address_space(3))) void*)(dst + o),
                16, 0, 0);
        }
    }
    __syncthreads();   // the ONLY block-wide sync in this kernel

    const int site_base = blk * SITES_PER_BLK + wave * SITES_PER_WAVE;

    const f32x4 ZERO = {0.f, 0.f, 0.f, 0.f};
    f32x4 acc[2][6];
    u32 gateb[2][6][2];
    float4 ra[4][4];   // A-prefetch ring, depth 4 (all indices compile-time)

// cc is compile-time at every expansion (chunk loop fully unrolled)
#define CH_A(cc)  ((cc) < NKZ ? z_ij : s_ij)
#define CH_KD(cc) ((cc) < NKZ ? CZ_ : C_)
#define CH_CK(cc) ((cc) < NKZ ? (cc) : (cc) - NKZ)

#define LOADA(ss, cc) do {                                                    \
        const float* _p0 = CH_A(cc) + (long)((ss) * NB_ + ln) * CH_KD(cc)     \
                           + CH_CK(cc) * 32 + q * 8;                          \
        const float* _p1 = _p0 + 16 * CH_KD(cc);                              \
        ra[(cc) & 3][0] = *reinterpret_cast<const float4*>(_p0);              \
        ra[(cc) & 3][1] = *reinterpret_cast<const float4*>(_p0 + 4);          \
        ra[(cc) & 3][2] = *reinterpret_cast<const float4*>(_p1);              \
        ra[(cc) & 3][3] = *reinterpret_cast<const float4*>(_p1 + 4);          \
    } while (0)

#define COMPUTE(cc) do {                                                      \
        bf16x8 _a0 = mk8(ra[(cc) & 3][0], ra[(cc) & 3][1]);                   \
        bf16x8 _a1 = mk8(ra[(cc) & 3][2], ra[(cc) & 3][3]);                   \
        const u16* _lw = &ldsW[(cc) * WCHUNK_U16 + q * 768 + ln * 8];         \
        _Pragma("unroll")                                                     \
        for (int _nt = 0; _nt < 6; ++_nt) {                                   \
            bf16x8 _b = *reinterpret_cast<const bf16x8*>(_lw + _nt * 128);    \
            acc[0][_nt] = __builtin_amdgcn_mfma_f32_16x16x32_bf16(            \
                _a0, _b, acc[0][_nt], 0, 0, 0);                               \
            acc[1][_nt] = __builtin_amdgcn_mfma_f32_16x16x32_bf16(            \
                _a1, _b, acc[1][_nt], 0, 0, 0);                               \
        }                                                                     \
    } while (0)

    // prologue: prefetch site_base chunks 0..3 (z phase)
    LOADA(site_base, 0); LOADA(site_base, 1);
    LOADA(site_base, 2); LOADA(site_base, 3);

    #pragma unroll 1
    for (int s4 = 0; s4 < SITES_PER_WAVE; ++s4) {
        const int site = site_base + s4;
        const int siten = (site + 1 < NSITES) ? site + 1 : site;  // next-site prefetch
        const float mv = m_ij[site * NB_ + (lane & 31)];

        #pragma unroll
        for (int mt = 0; mt < 2; ++mt)
            #pragma unroll
            for (int nt = 0; nt < 6; ++nt)
                acc[mt][nt] = ZERO;

        #pragma unroll
        for (int c = 0; c < NCH; ++c) {
            COMPUTE(c);               // consumes ra[c&3] ...
            if (c + 4 < NCH) LOADA(site, c + 4);     // ... then refill same slot
            else             LOADA(siten, c + 4 - NCH);  // next site's z chunks
            if (c == NKZ - 1) {
                // fold mask into gate, pack bf16, zero acc (register-only)
                #pragma unroll
                for (int mt = 0; mt < 2; ++mt) {
                    int rb = mt * 16 + q * 4;
                    float m0 = __shfl(mv, rb + 0, 64);
                    float m1 = __shfl(mv, rb + 1, 64);
                    float m2 = __shfl(mv, rb + 2, 64);
                    float m3 = __shfl(mv, rb + 3, 64);
                    #pragma unroll
                    for (int nt = 0; nt < 6; ++nt) {
                        gateb[mt][nt][0] = pk2(acc[mt][nt][0] * m0, acc[mt][nt][1] * m1);
                        gateb[mt][nt][1] = pk2(acc[mt][nt][2] * m2, acc[mt][nt][3] * m3);
                        acc[mt][nt] = ZERO;
                    }
                }
            }
        }

        // ---- epilogue: msg + neighbor reduction, write pre-LN to out ----
        // acc row = mt*16 + q*4 + r; col = strip*96 + nt*16 + ln
        const long obase = (long)site * C_ + strip * SCOLS;
        #pragma unroll
        for (int nt = 0; nt < 6; ++nt) {
            int col = nt * 16 + ln;
            float sii = s_i[obase + col];
            float p = 0.f;
            #pragma unroll
            for (int mt = 0; mt < 2; ++mt) {
                #pragma unroll
                for (int r = 0; r < 4; ++r) {
                    float gg = bfbits2f((u16)(gateb[mt][nt][r >> 1] >> ((r & 1) * 16)));
                    p += (acc[mt][nt][r] - sii) * gg;
                }
            }
            p += __shfl_xor(p, 16, 64);
            p += __shfl_xor(p, 32, 64);
            if (q == 0) out[obase + col] = p;
        }
    }

#undef LOADA
#undef COMPUTE
#undef CH_A
#undef CH_KD
#undef CH_CK
}

// In-place LayerNorm over the 384 cols of each site. 4 waves/block,
// one site per wave.
__global__ __launch_bounds__(256)
void ln_kernel(float* __restrict__ out,
               const float* __restrict__ gamma,
               const float* __restrict__ beta) {
    const int wave = threadIdx.x >> 6;
    const int lane = threadIdx.x & 63;
    const int site = blockIdx.x * 4 + wave;
    float v[6];
    float sum = 0.f, sumsq = 0.f;
    #pragma unroll
    for (int i = 0; i < 6; ++i) {
        v[i] = out[(long)site * C_ + lane + i * 64];
        sum += v[i];
        sumsq += v[i] * v[i];
    }
    #pragma unroll
    for (int off = 32; off >= 1; off >>= 1) {
        sum += __shfl_xor(sum, off, 64);
        sumsq += __shfl_xor(sumsq, off, 64);
    }
    float mu = sum * (1.f / C_);
    float var = sumsq * (1.f / C_) - mu * mu;
    float rs = rsqrtf(var + EPSV);
    #pragma unroll
    for (int i = 0; i < 6; ++i) {
        int col = lane + i * 64;
        out[(long)site * C_ + col] = (v[i] - mu) * rs * gamma[col] + beta[col];
    }
}

extern "C" void kernel_launch(void* const* d_in, const int* in_sizes, int n_in,
                              void* d_out, int out_size, void* d_ws, size_t ws_size,
                              hipStream_t stream) {
    (void)in_sizes; (void)n_in; (void)out_size; (void)ws_size;
    const float* s_i   = (const float*)d_in[0];
    const float* s_ij  = (const float*)d_in[1];
    const float* m_ij  = (const float*)d_in[2];
    const float* z_ij  = (const float*)d_in[3];
    const float* W_s   = (const float*)d_in[4];
    const float* W_z   = (const float*)d_in[5];
    const float* gamma = (const float*)d_in[6];
    const float* beta  = (const float*)d_in[7];
    float* out = (float*)d_out;

    u16* wsAll = (u16*)d_ws;   // 4 strips x 49152 u16 = 393216 B

    int prep_elems = NSTRIP * WSTRIP_U16;   // 196608
    prep_weights<<<(prep_elems + 255) / 256, 256, 0, stream>>>(W_s, W_z, wsAll);
    fused_msg_kernel<<<NSTRIP * NBLK, THREADS, 0, stream>>>(s_i, s_ij, m_ij, z_ij,
                                                            wsAll, out);
    ln_kernel<<<NSITES / 4, 256, 0, stream>>>(out, gamma, beta);
}

// Round 5
// 385.246 us; speedup vs baseline: 1.7243x; 1.7243x over previous
//
#include <hip/hip_runtime.h>
#include <hip/hip_bf16.h>

#define B_ 4
#define N_ 1024
#define NB_ 32
#define C_ 384
#define CZ_ 128
#define NSITES (B_ * N_)   // 4096
#define EPSV 1e-6f
#define SPB 2              // sites per block
#define THREADS 512
#define NKZ 4              // k-chunks for W_z (128/32)
#define NKS 12             // k-chunks for W_s (384/32)
#define WCH_U16 12288      // u16 per W chunk: 4 q * 384 d * 8 e (24576 B)
#define APLANE 528         // u16 stride between q-planes in ldsA (bank-spread)
#define ABUF_U16 (3 * APLANE + 512)   // 2096 u16 = 4192 B

typedef unsigned short u16;
typedef unsigned int u32;
typedef __bf16 bf16x8 __attribute__((ext_vector_type(8)));
typedef float f32x4 __attribute__((ext_vector_type(4)));

__device__ __forceinline__ u16 f2bf(float f) {
    return __builtin_bit_cast(u16, __float2bfloat16(f));
}
__device__ __forceinline__ u32 pk2(float lo, float hi) {
    return ((u32)f2bf(hi) << 16) | f2bf(lo);
}
__device__ __forceinline__ float bfbits2f(u16 u) {
    union { float f; u32 i; } x;
    x.i = ((u32)u) << 16;
    return x.f;
}

// Chunk-major fragment layout (R1's, measured SQ_LDS_BANK_CONFLICT == 0):
//   ws[((c*4 + q)*384 + d)*8 + e] = bf16(W[k][d]),  k = c*32 + q*8 + e
// Staged to LDS at the SAME linear offsets -> b-frag ds_read_b128 hits 16
// consecutive 16-B slots per 16-lane group.
__global__ void prep_weights(const float* __restrict__ Ws, const float* __restrict__ Wz,
                             u16* __restrict__ wsS, u16* __restrict__ wsZ) {
    int idx = blockIdx.x * 256 + threadIdx.x;
    const int NS = NKS * 4 * C_ * 8;   // 147456
    if (idx < NS) {
        int e = idx & 7, t = idx >> 3;
        int d = t % C_, u = t / C_;
        int q = u & 3, c = u >> 2;
        int k = c * 32 + q * 8 + e;
        wsS[idx] = f2bf(Ws[k * C_ + d]);
    } else {
        int j = idx - NS;
        if (j < NKZ * 4 * C_ * 8) {    // 49152
            int e = j & 7, t = j >> 3;
            int d = t % C_, u = t / C_;
            int q = u & 3, c = u >> 2;
            int k = c * 32 + q * 8 + e;
            wsZ[j] = f2bf(Wz[k * C_ + d]);
        }
    }
}

// R0's schedule EXACTLY (reg-prefetch a full compute-phase early, LDS-write
// late, 1 barrier/chunk, 2 sites/block, 8 waves = 2 sites x 4 col-strips).
// Only the LDS layouts changed:
//   W: [q][d][8] chunk-major (conflict-free reads, linear coalesced writes)
//   A: [q-plane][row][8], plane stride 528 u16 (conflict-free reads,
//      2-way=free writes: bank = 8q + 4(row%8) + 2(seg&1))
__global__ __launch_bounds__(THREADS, 4)
void fused_msg_kernel(const float* __restrict__ s_i,
                      const float* __restrict__ s_ij,
                      const float* __restrict__ m_ij,
                      const float* __restrict__ z_ij,
                      const u16* __restrict__ wsS,
                      const u16* __restrict__ wsZ,
                      const float* __restrict__ gamma,
                      const float* __restrict__ beta,
                      float* __restrict__ out) {
    __shared__ u16 ldsW[2][WCH_U16];    // 2 x 24576 B
    __shared__ u16 ldsA[2][ABUF_U16];   // 2 x  4192 B
    __shared__ float lds_snew[SPB * C_];//      3072 B   total 60608 B -> 2 blocks/CU

    const int tid = threadIdx.x;
    const int wave = tid >> 6;
    const int lane = tid & 63;
    const int q = lane >> 4;
    const int ln = lane & 15;
    const int mg = wave >> 2;            // site within the pair
    const int cb = (wave & 3) * 96;      // column strip base

    const int site0 = blockIdx.x * SPB;
    const long rowbase = (long)site0 * NB_;

    // staging maps (constant per thread)
    const int arow = tid >> 3, aseg = tid & 7;   // A: row 0..63, 4 floats at k=aseg*4
    const int la_w = (aseg >> 1) * APLANE + arow * 8 + (aseg & 1) * 4;  // u16
    const int lw_w = tid * 8;                                           // u16 (16B/thread)

    const float mv = m_ij[rowbase + lane];       // per-lane neighbor mask

    const f32x4 ZERO = {0.f, 0.f, 0.f, 0.f};
    f32x4 acc[2][6];
    #pragma unroll
    for (int mt = 0; mt < 2; ++mt)
        #pragma unroll
        for (int nt = 0; nt < 6; ++nt)
            acc[mt][nt] = ZERO;

    float4 ra;
    uint4 rw0, rw1, rw2;

    const int ra0 = q * APLANE + (mg * 32 + ln) * 8;   // a0 read offset (u16)
    const int wq0 = q * 3072;                          // W q-plane offset (u16)

    // -------- Phase 1: gate = z @ Wz (kd=128, NK=4) --------
    {
        const float* ap = z_ij + (rowbase + arow) * CZ_ + aseg * 4;
        const u16* wp = wsZ + lw_w;

        ra = *reinterpret_cast<const float4*>(ap);
        rw0 = *reinterpret_cast<const uint4*>(wp);
        rw1 = *reinterpret_cast<const uint4*>(wp + 4096);
        rw2 = *reinterpret_cast<const uint4*>(wp + 8192);
        ap += 32; wp += WCH_U16;
        {
            uint2 a2 = {pk2(ra.x, ra.y), pk2(ra.z, ra.w)};
            *reinterpret_cast<uint2*>(&ldsA[0][la_w]) = a2;
            *reinterpret_cast<uint4*>(&ldsW[0][lw_w]) = rw0;
            *reinterpret_cast<uint4*>(&ldsW[0][lw_w + 4096]) = rw1;
            *reinterpret_cast<uint4*>(&ldsW[0][lw_w + 8192]) = rw2;
        }
        __syncthreads();

        #pragma unroll 2
        for (int c = 0; c < NKZ; ++c) {
            if (c + 1 < NKZ) {
                ra = *reinterpret_cast<const float4*>(ap);
                rw0 = *reinterpret_cast<const uint4*>(wp);
                rw1 = *reinterpret_cast<const uint4*>(wp + 4096);
                rw2 = *reinterpret_cast<const uint4*>(wp + 8192);
                ap += 32; wp += WCH_U16;
            }
            const u16* lA = ldsA[c & 1];
            const u16* lW = ldsW[c & 1];
            bf16x8 a0 = *reinterpret_cast<const bf16x8*>(&lA[ra0]);
            bf16x8 a1 = *reinterpret_cast<const bf16x8*>(&lA[ra0 + 128]);
            #pragma unroll
            for (int nt = 0; nt < 6; ++nt) {
                bf16x8 b = *reinterpret_cast<const bf16x8*>(&lW[wq0 + (cb + nt * 16 + ln) * 8]);
                acc[0][nt] = __builtin_amdgcn_mfma_f32_16x16x32_bf16(a0, b, acc[0][nt], 0, 0, 0);
                acc[1][nt] = __builtin_amdgcn_mfma_f32_16x16x32_bf16(a1, b, acc[1][nt], 0, 0, 0);
            }
            if (c + 1 < NKZ) {
                int nb = (c + 1) & 1;
                uint2 a2 = {pk2(ra.x, ra.y), pk2(ra.z, ra.w)};
                *reinterpret_cast<uint2*>(&ldsA[nb][la_w]) = a2;
                *reinterpret_cast<uint4*>(&ldsW[nb][lw_w]) = rw0;
                *reinterpret_cast<uint4*>(&ldsW[nb][lw_w + 4096]) = rw1;
                *reinterpret_cast<uint4*>(&ldsW[nb][lw_w + 8192]) = rw2;
            }
            __syncthreads();
        }
    }

    // -------- Phase 2 chunk-0 global loads issued BEFORE the fold (T14:
    // the fold's VALU work covers their latency) --------
    const float* ap = s_ij + (rowbase + arow) * C_ + aseg * 4;
    const u16* wp = wsS + lw_w;
    ra = *reinterpret_cast<const float4*>(ap);
    rw0 = *reinterpret_cast<const uint4*>(wp);
    rw1 = *reinterpret_cast<const uint4*>(wp + 4096);
    rw2 = *reinterpret_cast<const uint4*>(wp + 8192);
    ap += 32; wp += WCH_U16;

    // fold mask into gate, pack bf16, zero acc (register-only)
    u32 gateb[2][6][2];
    #pragma unroll
    for (int mt = 0; mt < 2; ++mt) {
        int rb = mg * 32 + mt * 16 + q * 4;
        float m0 = __shfl(mv, rb + 0, 64);
        float m1 = __shfl(mv, rb + 1, 64);
        float m2 = __shfl(mv, rb + 2, 64);
        float m3 = __shfl(mv, rb + 3, 64);
        #pragma unroll
        for (int nt = 0; nt < 6; ++nt) {
            gateb[mt][nt][0] = pk2(acc[mt][nt][0] * m0, acc[mt][nt][1] * m1);
            gateb[mt][nt][1] = pk2(acc[mt][nt][2] * m2, acc[mt][nt][3] * m3);
            acc[mt][nt] = ZERO;
        }
    }

    // write phase-2 chunk 0 to buffer 0 (safe: buf0 last read at c=2 of
    // phase 1, before that iteration's barrier)
    {
        uint2 a2 = {pk2(ra.x, ra.y), pk2(ra.z, ra.w)};
        *reinterpret_cast<uint2*>(&ldsA[0][la_w]) = a2;
        *reinterpret_cast<uint4*>(&ldsW[0][lw_w]) = rw0;
        *reinterpret_cast<uint4*>(&ldsW[0][lw_w + 4096]) = rw1;
        *reinterpret_cast<uint4*>(&ldsW[0][lw_w + 8192]) = rw2;
    }
    __syncthreads();

    // -------- Phase 2: s_proj = s @ Ws (kd=384, NK=12) --------
    {
        #pragma unroll 2
        for (int c = 0; c < NKS; ++c) {
            if (c + 1 < NKS) {
                ra = *reinterpret_cast<const float4*>(ap);
                rw0 = *reinterpret_cast<const uint4*>(wp);
                rw1 = *reinterpret_cast<const uint4*>(wp + 4096);
                rw2 = *reinterpret_cast<const uint4*>(wp + 8192);
                ap += 32; wp += WCH_U16;
            }
            const u16* lA = ldsA[c & 1];
            const u16* lW = ldsW[c & 1];
            bf16x8 a0 = *reinterpret_cast<const bf16x8*>(&lA[ra0]);
            bf16x8 a1 = *reinterpret_cast<const bf16x8*>(&lA[ra0 + 128]);
            #pragma unroll
            for (int nt = 0; nt < 6; ++nt) {
                bf16x8 b = *reinterpret_cast<const bf16x8*>(&lW[wq0 + (cb + nt * 16 + ln) * 8]);
                acc[0][nt] = __builtin_amdgcn_mfma_f32_16x16x32_bf16(a0, b, acc[0][nt], 0, 0, 0);
                acc[1][nt] = __builtin_amdgcn_mfma_f32_16x16x32_bf16(a1, b, acc[1][nt], 0, 0, 0);
            }
            if (c + 1 < NKS) {
                int nb = (c + 1) & 1;
                uint2 a2 = {pk2(ra.x, ra.y), pk2(ra.z, ra.w)};
                *reinterpret_cast<uint2*>(&ldsA[nb][la_w]) = a2;
                *reinterpret_cast<uint4*>(&ldsW[nb][lw_w]) = rw0;
                *reinterpret_cast<uint4*>(&ldsW[nb][lw_w + 4096]) = rw1;
                *reinterpret_cast<uint4*>(&ldsW[nb][lw_w + 8192]) = rw2;
            }
            __syncthreads();
        }
    }

    // -------- Epilogue: msg + neighbor reduction --------
    // acc row = mg*32 + mt*16 + q*4 + r; col = cb + nt*16 + ln
    #pragma unroll
    for (int nt = 0; nt < 6; ++nt) {
        int col = cb + nt * 16 + ln;
        float si = s_i[(long)(site0 + mg) * C_ + col];
        float p = 0.f;
        #pragma unroll
        for (int mt = 0; mt < 2; ++mt) {
            #pragma unroll
            for (int r = 0; r < 4; ++r) {
                float g = bfbits2f((u16)(gateb[mt][nt][r >> 1] >> ((r & 1) * 16)));
                p += (acc[mt][nt][r] - si) * g;
            }
        }
        p += __shfl_xor(p, 16, 64);
        p += __shfl_xor(p, 32, 64);
        if (q == 0) lds_snew[mg * C_ + col] = p;
    }
    __syncthreads();

    // -------- LayerNorm: wave 0 -> site0, wave 1 -> site1 --------
    if (wave < SPB) {
        const int site = wave;
        float v[6];
        float sum = 0.f, sumsq = 0.f;
        #pragma unroll
        for (int i = 0; i < 6; ++i) {
            v[i] = lds_snew[site * C_ + lane + i * 64];
            sum += v[i];
            sumsq += v[i] * v[i];
        }
        #pragma unroll
        for (int off = 32; off >= 1; off >>= 1) {
            sum += __shfl_xor(sum, off, 64);
            sumsq += __shfl_xor(sumsq, off, 64);
        }
        float mu = sum * (1.f / C_);
        float var = sumsq * (1.f / C_) - mu * mu;
        float rs = rsqrtf(var + EPSV);
        #pragma unroll
        for (int i = 0; i < 6; ++i) {
            int col = lane + i * 64;
            out[(long)(site0 + site) * C_ + col] = (v[i] - mu) * rs * gamma[col] + beta[col];
        }
    }
}

extern "C" void kernel_launch(void* const* d_in, const int* in_sizes, int n_in,
                              void* d_out, int out_size, void* d_ws, size_t ws_size,
                              hipStream_t stream) {
    (void)in_sizes; (void)n_in; (void)out_size; (void)ws_size;
    const float* s_i   = (const float*)d_in[0];
    const float* s_ij  = (const float*)d_in[1];
    const float* m_ij  = (const float*)d_in[2];
    const float* z_ij  = (const float*)d_in[3];
    const float* W_s   = (const float*)d_in[4];
    const float* W_z   = (const float*)d_in[5];
    const float* gamma = (const float*)d_in[6];
    const float* beta  = (const float*)d_in[7];
    float* out = (float*)d_out;

    u16* wsS = (u16*)d_ws;                  // 12 chunks x 12288 u16
    u16* wsZ = wsS + NKS * 4 * C_ * 8;      //  4 chunks x 12288 u16

    int prep_elems = NKS * 4 * C_ * 8 + NKZ * 4 * C_ * 8;   // 196608
    prep_weights<<<(prep_elems + 255) / 256, 256, 0, stream>>>(W_s, W_z, wsS, wsZ);
    fused_msg_kernel<<<NSITES / SPB, THREADS, 0, stream>>>(s_i, s_ij, m_ij, z_ij,
                                                           wsS, wsZ, gamma, beta, out);
}